// Round 20
// baseline (37.948 us; speedup 1.0000x reference)
//
#include <hip/hip_runtime.h>
#include <math.h>

#define NT 64
#define L_LEN 720
#define NROWS (64 * 321)   // 20544, even

#define LOG2E 1.4426950408889634f
#define LN2   0.6931471805599453f

typedef float f32x2 __attribute__((ext_vector_type(2)));

__device__ __forceinline__ f32x2 pkfma(f32x2 a, f32x2 b, f32x2 c) {
    return __builtin_elementwise_fma(a, b, c);   // -> v_pk_fma_f32
}

// ---- DPP wave reductions: pure VALU pipe, no LDS, no lgkmcnt stalls ----
template<int CTRL, int RM>
__device__ __forceinline__ float dpp_add(float x) {
    int t = __builtin_amdgcn_update_dpp(0, __float_as_int(x), CTRL, RM, 0xf, true);
    return x + __int_as_float(t);
}

__device__ __forceinline__ float wave_sum64(float x) {
    x = dpp_add<0x111, 0xf>(x);   // row_shr:1
    x = dpp_add<0x112, 0xf>(x);   // row_shr:2
    x = dpp_add<0x114, 0xf>(x);   // row_shr:4
    x = dpp_add<0x118, 0xf>(x);   // row_shr:8
    x = dpp_add<0x142, 0xa>(x);   // row_bcast:15 -> rows 1,3
    x = dpp_add<0x143, 0xc>(x);   // row_bcast:31 -> rows 2,3 ; lane63 = total
    return __int_as_float(__builtin_amdgcn_readlane(__float_as_int(x), 63));
}

__device__ __forceinline__ float half_sum32(float x) {
    x = dpp_add<0x111, 0xf>(x);
    x = dpp_add<0x112, 0xf>(x);
    x = dpp_add<0x114, 0xf>(x);
    x = dpp_add<0x118, 0xf>(x);
    x = dpp_add<0x142, 0xa>(x);   // lane31 = sum lanes 0..31
    return __int_as_float(__builtin_amdgcn_readlane(__float_as_int(x), 31));
}

__global__ __launch_bounds__(NT, 4) void trend_kernel(
    const float* __restrict__ x,
    const float* __restrict__ cw0, const float* __restrict__ cb0,
    const float* __restrict__ cw1, const float* __restrict__ cb1,
    const float* __restrict__ cw2, const float* __restrict__ cb2,
    const float* __restrict__ cw3, const float* __restrict__ cb3,
    const float* __restrict__ W1, const float* __restrict__ b1,
    const float* __restrict__ W2, const float* __restrict__ b2,
    float* __restrict__ out)
{
    // TWO rows per wave: ALL 10 global loads issued at the head (one HBM
    // round-trip per 2 rows; 160B/lane in flight). fu-keep dropped to fit
    // cap 128; output recomputed as merged 9-tap conv from the live pairs.
    const int lane = threadIdx.x;            // 0..63
    const int rowA = blockIdx.x * 2;
    const int rowB = rowA + 1;

    const float* __restrict__ xa = x + (size_t)rowA * L_LEN;
    const float* __restrict__ xb = x + (size_t)rowB * L_LEN;

    // ---- ALL loads first (lanes 60..63 shadow lane 59; masked later)
    const int ll = (lane < 60) ? lane : 59;
    const int e0 = 12 * ll - 4;
    float xwA[20], xwB[20];
#pragma unroll
    for (int q = 0; q < 5; ++q) {
        int e = e0 + 4 * q;
        e = (e < 0) ? 0 : ((e > L_LEN - 4) ? (L_LEN - 4) : e);   // 16B-aligned
        float4 va = *(const float4*)(xa + e);
        float4 vb = *(const float4*)(xb + e);
        xwA[4 * q + 0] = va.x; xwA[4 * q + 1] = va.y;
        xwA[4 * q + 2] = va.z; xwA[4 * q + 3] = va.w;
        xwB[4 * q + 0] = vb.x; xwB[4 * q + 1] = vb.y;
        xwB[4 * q + 2] = vb.z; xwB[4 * q + 3] = vb.w;
    }

    // ---- MLP operand loads issued early (hide under conv)
    const int hidx = lane & 31;
    float w1r[4];
#pragma unroll
    for (int s = 0; s < 4; ++s) w1r[s] = W1[s * 32 + hidx];
    const float b1r = b1[hidx];
    const float4 w2v = ((const float4*)W2)[hidx];
    const float b20 = b2[0], b21 = b2[1], b22 = b2[2], b23 = b2[3];

    // ---- RAW conv weights: uniform addresses -> scalar loads (no VALU)
    const float* cws[4] = {cw0, cw1, cw2, cw3};
    const float* cbs[4] = {cb0, cb1, cb2, cb3};
    float w[4][9], bs[4];
#pragma unroll
    for (int s = 0; s < 4; ++s) {
        const int k = 3 + 2 * s;
        bs[s] = cbs[s][0];
#pragma unroll
        for (int t = 0; t < 9; ++t)
            w[s][t] = (t < k) ? cws[s][t] : 0.0f;
    }

    // row-edge zero padding
    if (lane == 0) {
#pragma unroll
        for (int t = 0; t < 4; ++t) { xwA[t] = 0.f; xwB[t] = 0.f; }
    }
    if (lane == 59) {
#pragma unroll
        for (int t = 16; t < 20; ++t) { xwA[t] = 0.f; xwB[t] = 0.f; }
    }

    // ---- stride-6 pair views (survive to the output pass); pin them
    f32x2 pA[14], pB[14];
#pragma unroll
    for (int i = 0; i < 14; ++i) {
        pA[i] = (f32x2){xwA[i], xwA[i + 6]};
        pB[i] = (f32x2){xwB[i], xwB[i + 6]};
    }
#pragma unroll
    for (int i = 0; i < 14; ++i) {
        asm volatile("" : "+v"(pA[i].x), "+v"(pA[i].y));
        asm volatile("" : "+v"(pB[i].x), "+v"(pB[i].y));
    }

    // ---- fused pass (both rows interleaved): conv f -> 2^(f*log2e) -> S,T
    const f32x2 l2e = (f32x2){LOG2E, LOG2E};
    f32x2 SpkA[4] = {{0,0},{0,0},{0,0},{0,0}}, SpkB[4] = {{0,0},{0,0},{0,0},{0,0}};
    f32x2 TpkA[4] = {{0,0},{0,0},{0,0},{0,0}}, TpkB[4] = {{0,0},{0,0},{0,0},{0,0}};
#pragma unroll
    for (int j = 0; j < 6; ++j) {
#pragma unroll
        for (int s = 0; s < 4; ++s) {
            const int k = 3 + 2 * s;
            const int off = 3 - s;              // 4 - k/2
            f32x2 fA = (f32x2){bs[s], bs[s]};
            f32x2 fB = fA;
#pragma unroll
            for (int t = 0; t < k; ++t) {
                const f32x2 wv = (f32x2){w[s][t], w[s][t]};
                fA = pkfma(wv, pA[j + off + t], fA);
                fB = pkfma(wv, pB[j + off + t], fB);
            }
            f32x2 uA = fA * l2e, uB = fB * l2e;
            f32x2 eA, eB;
            eA.x = __builtin_amdgcn_exp2f(uA.x);
            eA.y = __builtin_amdgcn_exp2f(uA.y);
            eB.x = __builtin_amdgcn_exp2f(uB.x);
            eB.y = __builtin_amdgcn_exp2f(uB.y);
            SpkA[s] += eA;                SpkB[s] += eB;
            TpkA[s] = pkfma(fA, eA, TpkA[s]);
            TpkB[s] = pkfma(fB, eB, TpkB[s]);
        }
    }

    // combine packed halves; mask lanes 60..63 (duplicates of 59)
    const bool active = lane < 60;
    float SA[4], TA[4], SB[4], TB[4];
#pragma unroll
    for (int s = 0; s < 4; ++s) {
        SA[s] = active ? (SpkA[s].x + SpkA[s].y) : 0.0f;
        TA[s] = active ? (TpkA[s].x + TpkA[s].y) : 0.0f;
        SB[s] = active ? (SpkB[s].x + SpkB[s].y) : 0.0f;
        TB[s] = active ? (TpkB[s].x + TpkB[s].y) : 0.0f;
    }

    // wave totals via DPP; entropy = ln2*log2(S) - T/S  (natural units)
    float entA[4], entB[4];
#pragma unroll
    for (int s = 0; s < 4; ++s) {
        float SgA = wave_sum64(SA[s]);
        float TgA = wave_sum64(TA[s]);
        float SgB = wave_sum64(SB[s]);
        float TgB = wave_sum64(TB[s]);
        entA[s] = fmaf(LN2, __builtin_amdgcn_logf(SgA),
                       -TgA * __builtin_amdgcn_rcpf(SgA));
        entB[s] = fmaf(LN2, __builtin_amdgcn_logf(SgB),
                       -TgB * __builtin_amdgcn_rcpf(SgB));
    }

    // MLP both rows; logits via DPP 32-lane sums
    float hA = b1r, hB = b1r;
#pragma unroll
    for (int s = 0; s < 4; ++s) {
        hA = fmaf(entA[s], w1r[s], hA);
        hB = fmaf(entB[s], w1r[s], hB);
    }
    hA = fmaxf(hA, 0.0f); hB = fmaxf(hB, 0.0f);

    float lgA0 = half_sum32(hA * w2v.x) + b20;
    float lgA1 = half_sum32(hA * w2v.y) + b21;
    float lgA2 = half_sum32(hA * w2v.z) + b22;
    float lgA3 = half_sum32(hA * w2v.w) + b23;
    float lgB0 = half_sum32(hB * w2v.x) + b20;
    float lgB1 = half_sum32(hB * w2v.y) + b21;
    float lgB2 = half_sum32(hB * w2v.z) + b22;
    float lgB3 = half_sum32(hB * w2v.w) + b23;

    // softmax per row (wave-uniform)
    float mA = fmaxf(fmaxf(lgA0, lgA1), fmaxf(lgA2, lgA3));
    float mB = fmaxf(fmaxf(lgB0, lgB1), fmaxf(lgB2, lgB3));
    float eA0 = __expf(lgA0 - mA), eA1 = __expf(lgA1 - mA);
    float eA2 = __expf(lgA2 - mA), eA3 = __expf(lgA3 - mA);
    float eB0 = __expf(lgB0 - mB), eB1 = __expf(lgB1 - mB);
    float eB2 = __expf(lgB2 - mB), eB3 = __expf(lgB3 - mB);
    float invA = 1.0f / (eA0 + eA1 + eA2 + eA3);
    float invB = 1.0f / (eB0 + eB1 + eB2 + eB3);
    const float wgtA[4] = {eA0 * invA, eA1 * invA, eA2 * invA, eA3 * invA};
    const float wgtB[4] = {eB0 * invB, eB1 * invB, eB2 * invB, eB3 * invB};

    // merged 9-tap output kernels per row (wave-uniform)
    float WmA[9] = {0,0,0,0,0,0,0,0,0}, WmB[9] = {0,0,0,0,0,0,0,0,0};
    float BmA = 0.f, BmB = 0.f;
#pragma unroll
    for (int s = 0; s < 4; ++s) {
        const int k = 3 + 2 * s;
        const int off = 3 - s;
#pragma unroll
        for (int t = 0; t < k; ++t) {
            WmA[off + t] = fmaf(wgtA[s], w[s][t], WmA[off + t]);
            WmB[off + t] = fmaf(wgtB[s], w[s][t], WmB[off + t]);
        }
        BmA = fmaf(wgtA[s], bs[s], BmA);
        BmB = fmaf(wgtB[s], bs[s], BmB);
    }

    // ---- output: merged packed conv from the pinned pairs, both rows
    if (active) {
        f32x2 oA[6], oB[6];
#pragma unroll
        for (int j = 0; j < 6; ++j) {
            f32x2 aA = (f32x2){BmA, BmA};
            f32x2 aB = (f32x2){BmB, BmB};
#pragma unroll
            for (int d = 0; d < 9; ++d) {
                aA = pkfma((f32x2){WmA[d], WmA[d]}, pA[j + d], aA);
                aB = pkfma((f32x2){WmB[d], WmB[d]}, pB[j + d], aB);
            }
            oA[j] = aA; oB[j] = aB;
        }
        float* __restrict__ oa = out + (size_t)rowA * L_LEN + 12 * lane;
        float* __restrict__ ob = out + (size_t)rowB * L_LEN + 12 * lane;
        float4 a0 = {oA[0].x, oA[1].x, oA[2].x, oA[3].x};
        float4 a1 = {oA[4].x, oA[5].x, oA[0].y, oA[1].y};
        float4 a2 = {oA[2].y, oA[3].y, oA[4].y, oA[5].y};
        float4 b0 = {oB[0].x, oB[1].x, oB[2].x, oB[3].x};
        float4 b1v = {oB[4].x, oB[5].x, oB[0].y, oB[1].y};
        float4 b2v = {oB[2].y, oB[3].y, oB[4].y, oB[5].y};
        *(float4*)(oa)     = a0;
        *(float4*)(oa + 4) = a1;
        *(float4*)(oa + 8) = a2;
        *(float4*)(ob)     = b0;
        *(float4*)(ob + 4) = b1v;
        *(float4*)(ob + 8) = b2v;
    }
}

extern "C" void kernel_launch(void* const* d_in, const int* in_sizes, int n_in,
                              void* d_out, int out_size, void* d_ws, size_t ws_size,
                              hipStream_t stream) {
    const float* xp  = (const float*)d_in[0];
    const float* cw0 = (const float*)d_in[1];
    const float* cb0 = (const float*)d_in[2];
    const float* cw1 = (const float*)d_in[3];
    const float* cb1 = (const float*)d_in[4];
    const float* cw2 = (const float*)d_in[5];
    const float* cb2 = (const float*)d_in[6];
    const float* cw3 = (const float*)d_in[7];
    const float* cb3 = (const float*)d_in[8];
    const float* W1  = (const float*)d_in[9];
    const float* b1  = (const float*)d_in[10];
    const float* W2  = (const float*)d_in[11];
    const float* b2  = (const float*)d_in[12];
    float* outp = (float*)d_out;

    trend_kernel<<<NROWS / 2, NT, 0, stream>>>(xp, cw0, cb0, cw1, cb1, cw2, cb2,
                                               cw3, cb3, W1, b1, W2, b2, outp);
}

// Round 21
// 33.551 us; speedup vs baseline: 1.1311x; 1.1311x over previous
//
#include <hip/hip_runtime.h>
#include <math.h>

#define NT 64
#define L_LEN 720
#define NROWS (64 * 321)   // 20544

#define LOG2E 1.4426950408889634f
#define LN2   0.6931471805599453f

typedef float f32x2 __attribute__((ext_vector_type(2)));

__device__ __forceinline__ f32x2 pkfma(f32x2 a, f32x2 b, f32x2 c) {
    return __builtin_elementwise_fma(a, b, c);   // -> v_pk_fma_f32
}

// ---- DPP wave reductions: pure VALU pipe, no LDS, no lgkmcnt stalls ----
template<int CTRL, int RM>
__device__ __forceinline__ float dpp_add(float x) {
    int t = __builtin_amdgcn_update_dpp(0, __float_as_int(x), CTRL, RM, 0xf, true);
    return x + __int_as_float(t);
}

// lane-shift across the whole wave; out-of-range lanes read 0 (bound_ctrl)
template<int CTRL>
__device__ __forceinline__ float dpp_shift(float x) {
    int t = __builtin_amdgcn_update_dpp(0, __float_as_int(x), CTRL, 0xf, 0xf, true);
    return __int_as_float(t);
}
#define WAVE_SHL1 0x130   // lane i <- lane i+1
#define WAVE_SHR1 0x138   // lane i <- lane i-1

__device__ __forceinline__ float wave_sum64(float x) {
    x = dpp_add<0x111, 0xf>(x);   // row_shr:1
    x = dpp_add<0x112, 0xf>(x);   // row_shr:2
    x = dpp_add<0x114, 0xf>(x);   // row_shr:4
    x = dpp_add<0x118, 0xf>(x);   // row_shr:8
    x = dpp_add<0x142, 0xa>(x);   // row_bcast:15 -> rows 1,3
    x = dpp_add<0x143, 0xc>(x);   // row_bcast:31 -> rows 2,3 ; lane63 = total
    return __int_as_float(__builtin_amdgcn_readlane(__float_as_int(x), 63));
}

__device__ __forceinline__ float half_sum32(float x) {
    x = dpp_add<0x111, 0xf>(x);
    x = dpp_add<0x112, 0xf>(x);
    x = dpp_add<0x114, 0xf>(x);
    x = dpp_add<0x118, 0xf>(x);
    x = dpp_add<0x142, 0xa>(x);   // lane31 = sum lanes 0..31
    return __int_as_float(__builtin_amdgcn_readlane(__float_as_int(x), 31));
}

__global__ __launch_bounds__(NT, 4) void trend_kernel(
    const float* __restrict__ x,
    const float* __restrict__ cw0, const float* __restrict__ cb0,
    const float* __restrict__ cw1, const float* __restrict__ cb1,
    const float* __restrict__ cw2, const float* __restrict__ cb2,
    const float* __restrict__ cw3, const float* __restrict__ cb3,
    const float* __restrict__ W1, const float* __restrict__ b1,
    const float* __restrict__ W2, const float* __restrict__ b2,
    float* __restrict__ out)
{
    // R18 champion body, loads minimized: 3 exact core float4 loads per lane
    // (48B owned, 48B loaded); the 4+4 halo elements come from NEIGHBOR LANE
    // REGISTERS via v_mov_dpp wave_shr:1 / wave_shl:1 (bound_ctrl gives free
    // zero-padding at lane 0 / 63). No clamp math, no overlapping fetch.
    const int lane = threadIdx.x;            // 0..63
    const int row  = blockIdx.x;

    const float*  __restrict__ xr = x + (size_t)row * L_LEN;
    const float4* __restrict__ xc = (const float4*)xr;

    const int  ll     = (lane < 60) ? lane : 59;   // lanes 60..63 shadow 59
    const bool active = lane < 60;

    // ---- 3 exact core loads: elements 12*ll .. 12*ll+11
    float4 c0 = xc[3 * ll + 0];
    float4 c1 = xc[3 * ll + 1];
    float4 c2 = xc[3 * ll + 2];

    // ---- MLP operand loads issued early (hide under conv)
    const int hidx = lane & 31;
    float w1r[4];
#pragma unroll
    for (int s = 0; s < 4; ++s) w1r[s] = W1[s * 32 + hidx];
    const float b1r = b1[hidx];
    const float4 w2v = ((const float4*)W2)[hidx];
    const float b20 = b2[0], b21 = b2[1], b22 = b2[2], b23 = b2[3];

    // ---- RAW conv weights: uniform addresses -> scalar loads (no VALU)
    const float* cws[4] = {cw0, cw1, cw2, cw3};
    const float* cbs[4] = {cb0, cb1, cb2, cb3};
    float w[4][9], bs[4];
#pragma unroll
    for (int s = 0; s < 4; ++s) {
        const int k = 3 + 2 * s;
        bs[s] = cbs[s][0];
#pragma unroll
        for (int t = 0; t < 9; ++t)
            w[s][t] = (t < k) ? cws[s][t] : 0.0f;
    }

    // ---- halo from neighbor lanes' registers (8 v_mov_dpp)
    // left halo (elements 12*ll-4 .. -1) = lane-1's c2 ; lane 0 -> 0 free
    float xw[20];
    xw[0] = dpp_shift<WAVE_SHR1>(c2.x);
    xw[1] = dpp_shift<WAVE_SHR1>(c2.y);
    xw[2] = dpp_shift<WAVE_SHR1>(c2.z);
    xw[3] = dpp_shift<WAVE_SHR1>(c2.w);
    xw[4]  = c0.x; xw[5]  = c0.y; xw[6]  = c0.z; xw[7]  = c0.w;
    xw[8]  = c1.x; xw[9]  = c1.y; xw[10] = c1.z; xw[11] = c1.w;
    xw[12] = c2.x; xw[13] = c2.y; xw[14] = c2.z; xw[15] = c2.w;
    // right halo (elements 12*ll+12 .. +15) = lane+1's c0 ; lane 63 -> 0 free
    xw[16] = dpp_shift<WAVE_SHL1>(c0.x);
    xw[17] = dpp_shift<WAVE_SHL1>(c0.y);
    xw[18] = dpp_shift<WAVE_SHL1>(c0.z);
    xw[19] = dpp_shift<WAVE_SHL1>(c0.w);
    // lane 59's right neighbor (lane 60) holds duplicate data, not row-end zeros
    if (lane == 59) { xw[16] = 0.f; xw[17] = 0.f; xw[18] = 0.f; xw[19] = 0.f; }

    // pin window (loaded/built exactly once, no remat/re-fetch)
#pragma unroll
    for (int t = 0; t < 20; ++t) asm volatile("" : "+v"(xw[t]));

    // ---- stride-6 pair view: p[i] = (xw[i], xw[i+6]), i = 0..13
    f32x2 p[14];
#pragma unroll
    for (int i = 0; i < 14; ++i) p[i] = (f32x2){xw[i], xw[i + 6]};

    // ---- fused pass: conv f (natural) kept in regs -> u = f*log2e (packed)
    //      -> 2^u -> accumulate S (=sum e^f), Tn (=sum f e^f)
    const f32x2 l2e = (f32x2){LOG2E, LOG2E};
    f32x2 fu[4][6];
    f32x2 Spk[4] = {{0.f,0.f},{0.f,0.f},{0.f,0.f},{0.f,0.f}};
    f32x2 Tpk[4] = {{0.f,0.f},{0.f,0.f},{0.f,0.f},{0.f,0.f}};
#pragma unroll
    for (int j = 0; j < 6; ++j) {
#pragma unroll
        for (int s = 0; s < 4; ++s) {
            const int k = 3 + 2 * s;
            const int off = 3 - s;              // 4 - k/2
            f32x2 f = (f32x2){bs[s], bs[s]};
#pragma unroll
            for (int t = 0; t < k; ++t) {
                const f32x2 wv = (f32x2){w[s][t], w[s][t]};
                f = pkfma(wv, p[j + off + t], f);
            }
            fu[s][j] = f;
            f32x2 u = f * l2e;                  // one v_pk_mul
            f32x2 ev;
            ev.x = __builtin_amdgcn_exp2f(u.x);
            ev.y = __builtin_amdgcn_exp2f(u.y);
            Spk[s] += ev;
            Tpk[s] = pkfma(f, ev, Tpk[s]);      // natural units
        }
    }

    // pin fu: conv computed exactly once (no remat through the tail)
#pragma unroll
    for (int s = 0; s < 4; ++s)
#pragma unroll
        for (int j = 0; j < 6; ++j)
            asm volatile("" : "+v"(fu[s][j].x), "+v"(fu[s][j].y));

    // combine packed halves; mask lanes 60..63 (duplicates of 59)
    float S[4], Tn[4];
#pragma unroll
    for (int s = 0; s < 4; ++s) {
        S[s]  = active ? (Spk[s].x + Spk[s].y) : 0.0f;
        Tn[s] = active ? (Tpk[s].x + Tpk[s].y) : 0.0f;
    }

    // wave totals via DPP; entropy = ln2*log2(S) - Tn/S
    float ent[4];
#pragma unroll
    for (int s = 0; s < 4; ++s) {
        float Sg = wave_sum64(S[s]);
        float Tg = wave_sum64(Tn[s]);
        ent[s] = fmaf(LN2, __builtin_amdgcn_logf(Sg),
                      -Tg * __builtin_amdgcn_rcpf(Sg));
    }

    // MLP: hidden unit per lane (mod 32); logits via DPP 32-lane sums
    float h = b1r;
#pragma unroll
    for (int s = 0; s < 4; ++s) h = fmaf(ent[s], w1r[s], h);
    h = fmaxf(h, 0.0f);

    float lg0 = half_sum32(h * w2v.x) + b20;
    float lg1 = half_sum32(h * w2v.y) + b21;
    float lg2 = half_sum32(h * w2v.z) + b22;
    float lg3 = half_sum32(h * w2v.w) + b23;

    // softmax (wave-uniform); weights apply to natural f directly
    float m = fmaxf(fmaxf(lg0, lg1), fmaxf(lg2, lg3));
    float e0w = __expf(lg0 - m), e1w = __expf(lg1 - m);
    float e2w = __expf(lg2 - m), e3w = __expf(lg3 - m);
    float inv = 1.0f / (e0w + e1w + e2w + e3w);
    const float wg0 = e0w * inv, wg1 = e1w * inv;
    const float wg2 = e2w * inv, wg3 = e3w * inv;

    // ---- output directly from the kept natural-unit f pairs: 4 pkfma/pair
    if (active) {
        f32x2 o[6];
#pragma unroll
        for (int j = 0; j < 6; ++j) {
            f32x2 acc = (f32x2){wg0, wg0} * fu[0][j];
            acc = pkfma((f32x2){wg1, wg1}, fu[1][j], acc);
            acc = pkfma((f32x2){wg2, wg2}, fu[2][j], acc);
            acc = pkfma((f32x2){wg3, wg3}, fu[3][j], acc);
            o[j] = acc;
        }
        // elements: j -> o[j].x (0..5), j+6 -> o[j].y (6..11); repack to float4
        float* __restrict__ orow = out + (size_t)row * L_LEN + 12 * lane;
        float4 v0 = {o[0].x, o[1].x, o[2].x, o[3].x};
        float4 v1 = {o[4].x, o[5].x, o[0].y, o[1].y};
        float4 v2 = {o[2].y, o[3].y, o[4].y, o[5].y};
        *(float4*)(orow)     = v0;
        *(float4*)(orow + 4) = v1;
        *(float4*)(orow + 8) = v2;
    }
}

extern "C" void kernel_launch(void* const* d_in, const int* in_sizes, int n_in,
                              void* d_out, int out_size, void* d_ws, size_t ws_size,
                              hipStream_t stream) {
    const float* xp  = (const float*)d_in[0];
    const float* cw0 = (const float*)d_in[1];
    const float* cb0 = (const float*)d_in[2];
    const float* cw1 = (const float*)d_in[3];
    const float* cb1 = (const float*)d_in[4];
    const float* cw2 = (const float*)d_in[5];
    const float* cb2 = (const float*)d_in[6];
    const float* cw3 = (const float*)d_in[7];
    const float* cb3 = (const float*)d_in[8];
    const float* W1  = (const float*)d_in[9];
    const float* b1  = (const float*)d_in[10];
    const float* W2  = (const float*)d_in[11];
    const float* b2  = (const float*)d_in[12];
    float* outp = (float*)d_out;

    trend_kernel<<<NROWS, NT, 0, stream>>>(xp, cw0, cb0, cw1, cb1, cw2, cb2,
                                           cw3, cb3, W1, b1, W2, b2, outp);
}

// Round 22
// 32.836 us; speedup vs baseline: 1.1557x; 1.0218x over previous
//
#include <hip/hip_runtime.h>
#include <math.h>

#define NT 64
#define L_LEN 720
#define NROWS (64 * 321)   // 20544

#define LOG2E 1.4426950408889634f
#define LN2   0.6931471805599453f

typedef float f32x2 __attribute__((ext_vector_type(2)));

__device__ __forceinline__ f32x2 pkfma(f32x2 a, f32x2 b, f32x2 c) {
    return __builtin_elementwise_fma(a, b, c);   // -> v_pk_fma_f32
}

// uniform float -> SGPR (frees a VGPR; pkfma may read 1 SGPR operand)
__device__ __forceinline__ float rfl(float v) {
    return __int_as_float(__builtin_amdgcn_readfirstlane(__float_as_int(v)));
}

// ---- DPP wave reductions: pure VALU pipe, no LDS, no lgkmcnt stalls ----
template<int CTRL, int RM>
__device__ __forceinline__ float dpp_add(float x) {
    int t = __builtin_amdgcn_update_dpp(0, __float_as_int(x), CTRL, RM, 0xf, true);
    return x + __int_as_float(t);
}

__device__ __forceinline__ float wave_sum64(float x) {
    x = dpp_add<0x111, 0xf>(x);   // row_shr:1
    x = dpp_add<0x112, 0xf>(x);   // row_shr:2
    x = dpp_add<0x114, 0xf>(x);   // row_shr:4
    x = dpp_add<0x118, 0xf>(x);   // row_shr:8
    x = dpp_add<0x142, 0xa>(x);   // row_bcast:15 -> rows 1,3
    x = dpp_add<0x143, 0xc>(x);   // row_bcast:31 -> rows 2,3 ; lane63 = total
    return __int_as_float(__builtin_amdgcn_readlane(__float_as_int(x), 63));
}

__device__ __forceinline__ float half_sum32(float x) {
    x = dpp_add<0x111, 0xf>(x);
    x = dpp_add<0x112, 0xf>(x);
    x = dpp_add<0x114, 0xf>(x);
    x = dpp_add<0x118, 0xf>(x);
    x = dpp_add<0x142, 0xa>(x);   // lane31 = sum lanes 0..31
    return __int_as_float(__builtin_amdgcn_readlane(__float_as_int(x), 31));
}

__global__ __launch_bounds__(NT, 4) void trend_kernel(
    const float* __restrict__ x,
    const float* __restrict__ cw0, const float* __restrict__ cb0,
    const float* __restrict__ cw1, const float* __restrict__ cb1,
    const float* __restrict__ cw2, const float* __restrict__ cb2,
    const float* __restrict__ cw3, const float* __restrict__ cb3,
    const float* __restrict__ W1, const float* __restrict__ b1,
    const float* __restrict__ W2, const float* __restrict__ b2,
    float* __restrict__ out)
{
    // CHAMPION (R15 body, 32.96 us): 1 wave/block, packed-fp32 conv/exp core,
    // conv outputs kept in regs (no 2nd conv, no merge), SGPR weights, DPP-only
    // reductions. Cap-128 VGPR budget (the only spill-free configuration).
    const int lane = threadIdx.x;            // 0..63
    const int row  = blockIdx.x;

    const float* __restrict__ xr = x + (size_t)row * L_LEN;

    // ---- loads first (lanes 60..63 shadow lane 59; masked later)
    const int ll = (lane < 60) ? lane : 59;
    const int e0 = 12 * ll - 4;
    float xw[20];
#pragma unroll
    for (int q = 0; q < 5; ++q) {
        int e = e0 + 4 * q;
        e = (e < 0) ? 0 : ((e > L_LEN - 4) ? (L_LEN - 4) : e);   // 16B-aligned
        float4 v = *(const float4*)(xr + e);
        xw[4 * q + 0] = v.x; xw[4 * q + 1] = v.y;
        xw[4 * q + 2] = v.z; xw[4 * q + 3] = v.w;
    }

    // ---- uniform weights -> SGPRs under the load shadow (LOG2E pre-folded)
    const float* cws[4] = {cw0, cw1, cw2, cw3};
    const float* cbs[4] = {cb0, cb1, cb2, cb3};
    float w2[4][9], bs2[4];
#pragma unroll
    for (int s = 0; s < 4; ++s) {
        const int k = 3 + 2 * s;
        bs2[s] = rfl(cbs[s][0] * LOG2E);
#pragma unroll
        for (int t = 0; t < 9; ++t)
            w2[s][t] = (t < k) ? rfl(cws[s][t] * LOG2E) : 0.0f;
    }

    // row-edge zero padding
    if (lane == 0)  { xw[0] = 0.f; xw[1] = 0.f; xw[2] = 0.f; xw[3] = 0.f; }
    if (lane == 59) { xw[16] = 0.f; xw[17] = 0.f; xw[18] = 0.f; xw[19] = 0.f; }

    // pin window (loads happen exactly once)
#pragma unroll
    for (int t = 0; t < 20; ++t) asm volatile("" : "+v"(xw[t]));

    // ---- stride-6 pair view: p[i] = (xw[i], xw[i+6]), i = 0..13
    f32x2 p[14];
#pragma unroll
    for (int i = 0; i < 14; ++i) p[i] = (f32x2){xw[i], xw[i + 6]};

    // ---- fused pass: conv(u) kept in regs -> 2^u -> accumulate S, Tu
    f32x2 fu[4][6];
    f32x2 Spk[4] = {{0.f,0.f},{0.f,0.f},{0.f,0.f},{0.f,0.f}};
    f32x2 Tpk[4] = {{0.f,0.f},{0.f,0.f},{0.f,0.f},{0.f,0.f}};
#pragma unroll
    for (int j = 0; j < 6; ++j) {
#pragma unroll
        for (int s = 0; s < 4; ++s) {
            const int k = 3 + 2 * s;
            const int off = 3 - s;              // 4 - k/2
            f32x2 u = (f32x2){bs2[s], bs2[s]};
#pragma unroll
            for (int t = 0; t < k; ++t) {
                const f32x2 wv = (f32x2){w2[s][t], w2[s][t]};
                u = pkfma(wv, p[j + off + t], u);
            }
            fu[s][j] = u;
            f32x2 ev;
            ev.x = __builtin_amdgcn_exp2f(u.x);
            ev.y = __builtin_amdgcn_exp2f(u.y);
            Spk[s] += ev;
            Tpk[s] = pkfma(u, ev, Tpk[s]);
        }
    }

    // pin fu: conv computed exactly once (no remat through the tail)
#pragma unroll
    for (int s = 0; s < 4; ++s)
#pragma unroll
        for (int j = 0; j < 6; ++j) {
            asm volatile("" : "+v"(fu[s][j].x));
            asm volatile("" : "+v"(fu[s][j].y));
        }

    // combine packed halves; mask lanes 60..63 (duplicates of 59)
    const bool active = lane < 60;
    float S[4], Tu[4];
#pragma unroll
    for (int s = 0; s < 4; ++s) {
        S[s]  = active ? (Spk[s].x + Spk[s].y) : 0.0f;
        Tu[s] = active ? (Tpk[s].x + Tpk[s].y) : 0.0f;
    }

    // wave totals via DPP; entropy = ln2 * (log2 S - Tu/S), wave-uniform
    float ent[4];
#pragma unroll
    for (int s = 0; s < 4; ++s) {
        float Sg = wave_sum64(S[s]);
        float Tg = wave_sum64(Tu[s]);
        ent[s] = LN2 * (__builtin_amdgcn_logf(Sg)
                        - Tg * __builtin_amdgcn_rcpf(Sg));
    }

    // MLP: hidden unit per lane (mod 32); logits via DPP 32-lane sums
    const int hidx = lane & 31;
    float h = b1[hidx];
#pragma unroll
    for (int s = 0; s < 4; ++s) h = fmaf(ent[s], W1[s * 32 + hidx], h);
    h = fmaxf(h, 0.0f);

    const float4 w2v = ((const float4*)W2)[hidx];
    float lg0 = half_sum32(h * w2v.x) + b2[0];
    float lg1 = half_sum32(h * w2v.y) + b2[1];
    float lg2 = half_sum32(h * w2v.z) + b2[2];
    float lg3 = half_sum32(h * w2v.w) + b2[3];

    // softmax (wave-uniform); LN2 folded so wgt' applies directly to u:
    // out = sum_s wgt_s * f_s = ln2 * sum_s wgt_s * u_s
    float m = fmaxf(fmaxf(lg0, lg1), fmaxf(lg2, lg3));
    float e0w = __expf(lg0 - m), e1w = __expf(lg1 - m);
    float e2w = __expf(lg2 - m), e3w = __expf(lg3 - m);
    float inv = LN2 / (e0w + e1w + e2w + e3w);
    const float wg0 = e0w * inv, wg1 = e1w * inv;
    const float wg2 = e2w * inv, wg3 = e3w * inv;

    // ---- output directly from the kept u pairs: 4 pkfma per pair
    if (active) {
        f32x2 o[6];
#pragma unroll
        for (int j = 0; j < 6; ++j) {
            f32x2 acc = (f32x2){wg0, wg0} * fu[0][j];
            acc = pkfma((f32x2){wg1, wg1}, fu[1][j], acc);
            acc = pkfma((f32x2){wg2, wg2}, fu[2][j], acc);
            acc = pkfma((f32x2){wg3, wg3}, fu[3][j], acc);
            o[j] = acc;
        }
        // elements: j -> o[j].x (0..5), j+6 -> o[j].y (6..11); repack to float4
        float* __restrict__ orow = out + (size_t)row * L_LEN + 12 * lane;
        float4 v0 = {o[0].x, o[1].x, o[2].x, o[3].x};
        float4 v1 = {o[4].x, o[5].x, o[0].y, o[1].y};
        float4 v2 = {o[2].y, o[3].y, o[4].y, o[5].y};
        *(float4*)(orow)     = v0;
        *(float4*)(orow + 4) = v1;
        *(float4*)(orow + 8) = v2;
    }
}

extern "C" void kernel_launch(void* const* d_in, const int* in_sizes, int n_in,
                              void* d_out, int out_size, void* d_ws, size_t ws_size,
                              hipStream_t stream) {
    const float* xp  = (const float*)d_in[0];
    const float* cw0 = (const float*)d_in[1];
    const float* cb0 = (const float*)d_in[2];
    const float* cw1 = (const float*)d_in[3];
    const float* cb1 = (const float*)d_in[4];
    const float* cw2 = (const float*)d_in[5];
    const float* cb2 = (const float*)d_in[6];
    const float* cw3 = (const float*)d_in[7];
    const float* cb3 = (const float*)d_in[8];
    const float* W1  = (const float*)d_in[9];
    const float* b1  = (const float*)d_in[10];
    const float* W2  = (const float*)d_in[11];
    const float* b2  = (const float*)d_in[12];
    float* outp = (float*)d_out;

    trend_kernel<<<NROWS, NT, 0, stream>>>(xp, cw0, cb0, cw1, cb1, cw2, cb2,
                                           cw3, cb3, W1, b1, W2, b2, outp);
}